// Round 14
// baseline (1388.800 us; speedup 1.0000x reference)
//
#include <hip/hip_runtime.h>
#include <hip/hip_bf16.h>
#include <math.h>

typedef unsigned int u32;

#define B_ 128
#define S_ 128
#define T_ 127
#define D_ 100
#define QN_ 4
#define SN_ 4
#define KC_ 4
#define RK_ 10
#define NEGV -1000000000.0f

__device__ __forceinline__ float sigmf(float x) { return 1.0f / (1.0f + expf(-x)); }

__device__ __forceinline__ u32 f2bfbits(float x) {
  __hip_bfloat16 h = __float2bfloat16(x);
  unsigned short s;
  __builtin_memcpy(&s, &h, 2);
  return (u32)s;
}

// ---------------------------------------------------------------------------
// Setup (unchanged): transposed f32 weights for phaseA/B; erw fold;
// kw0 scalar; bf16 lane-swizzled weight image (1792 slots x 64 u32 = 256B):
//   [0,300): W_hh1 | [300,600): W_hh2 | [1024,1324): W_ih2 | [1536,1636): W_query
// slot bytes: [sub(4)][k(16 u32)], u32 k packs bf16 cols (sub*25+2k, +2k+1).
// ---------------------------------------------------------------------------
__global__ __launch_bounds__(256) void setupk(
    const float* Er, const float* W_ih1, const float* b_ih1,
    const float* Wagg, const float* W_last, const float* W_key,
    const float* b_query, const float* W_W, const float* W_query,
    const float* W_hh1, const float* W_hh2, const float* W_ih2,
    const float* b_hh1, const float* b_hh2, const float* b_ih2,
    float* wih1aT, float* erw, float* waggT, float* wlastT, float* wkeyT,
    float* scal, u32* wcat16, float* bcat)
{
  int gid = blockIdx.x * blockDim.x + threadIdx.x;
  int gsz = gridDim.x * blockDim.x;

  for (int x = gid; x < 30000; x += gsz) {
    int j = x / 300, i = x % 300;
    wih1aT[j * 300 + i] = W_ih1[i * 200 + j];
  }
  for (int x = gid; x < 600; x += gsz) {
    int r = x / 300, i = x % 300;
    float acc = b_ih1[i];
    for (int j = 0; j < 100; j++) acc += Er[r * 100 + j] * W_ih1[i * 200 + 100 + j];
    erw[x] = acc;
  }
  for (int x = gid; x < 30000; x += gsz) {
    int h = x / 10000, rr = x % 10000, j = rr / 100, i = rr % 100;
    waggT[h * 10000 + j * 100 + i] = Wagg[h * 10000 + i * 100 + j];
  }
  for (int x = gid; x < 10000; x += gsz) {
    int j = x / 100, i = x % 100;
    wlastT[j * 100 + i] = W_last[i * 100 + j];
    wkeyT[j * 100 + i] = W_key[i * 100 + j];
  }
  for (int x = gid; x < 114688; x += gsz) {
    int slot = x / 64, rem = x % 64, sbu = rem / 16, k = rem % 16;
    const float* src = nullptr;
    if (slot < 300)                       src = W_hh1 + (size_t)slot * 100;
    else if (slot < 600)                  src = W_hh2 + (size_t)(slot - 300) * 100;
    else if (slot >= 1024 && slot < 1324) src = W_ih2 + (size_t)(slot - 1024) * 100;
    else if (slot >= 1536 && slot < 1636) src = W_query + (size_t)(slot - 1536) * 100;
    u32 lo = 0, hi = 0;
    if (src) {
      int e0 = 2 * k, e1 = 2 * k + 1;
      if (e0 < 25) lo = f2bfbits(src[sbu * 25 + e0]);
      if (e1 < 25) hi = f2bfbits(src[sbu * 25 + e1]);
    }
    wcat16[x] = (hi << 16) | lo;
  }
  for (int x = gid; x < 1792; x += gsz) {
    float v = 0.f;
    if (x < 300) v = b_hh1[x];
    else if (x < 600) v = b_hh2[x - 300];
    else if (x >= 1024 && x < 1324) v = b_ih2[x - 1024];
    else if (x >= 1536 && x < 1636) v = b_query[x - 1536];
    bcat[x] = v;
  }
  if (gid == 0) {
    float acc = 0.f;  // kw of the all-zero hist state: dot(tanh(b_query), Wk_part)
    for (int i = 0; i < 100; i++) acc += tanhf(b_query[i]) * W_W[100 + i];
    scal[0] = acc;
  }
}

// ---------------------------------------------------------------------------
// Phase A v5: R11's W-column-sharing structure at 512 THREADS/BLOCK.
// Pass1's critical path is per-thread item count: 600 items over 256 threads
// = 3 items (7 units) on threads 0-87; over 512 threads = 2 items (4 units)
// max. Gather/staging loops also halve per-thread. Pure width change: no
// vector loads (R8 failure), no unroll pragmas (R9 failure), identical
// per-item code -> same register class. LDS 26KB; 512 thr -> 4 blocks/CU
// (thread-capped), resident waves unchanged. Numerics bit-identical.
// ---------------------------------------------------------------------------
__global__ __launch_bounds__(512) void phaseA(
    const float* Eq, const float* Ec, const int* question, const int* response, const int* mask,
    const int* qnb, const int* snb,
    const float* wih1aT, const float* erw, const float* waggT, const float* wlastT,
    const float* baggf, const float* blastf, float* gi1_all)
{
  const int t = blockIdx.x, b = blockIdx.y, tid = threadIdx.x;
  __shared__ float e0[100], ne0[100], e1[400], ne1[400];
  __shared__ float e2[1600], ne2[1600], m3[1600];
  __shared__ float sum4[400], sum1[100], emq[100];
  __shared__ int l1[4], l2[16], l3[64];

  const int qt = question[b * S_ + t];
  const int mt = mask[b * S_ + t];
  const int rt = response[b * S_ + t];

  if (mt != 0) {
    if (tid < 4) l1[tid] = qnb[qt * QN_ + tid];
    for (int x = tid; x < 100; x += 512) e0[x] = Eq[(size_t)qt * 100 + x];
    __syncthreads();
    if (tid < 16) l2[tid] = snb[l1[tid >> 2] * SN_ + (tid & 3)];
    for (int x = tid; x < 400; x += 512) e1[x] = Ec[(size_t)l1[x / 100] * 100 + (x % 100)];
    __syncthreads();
    if (tid < 64) l3[tid] = qnb[l2[tid >> 2] * QN_ + (tid & 3)];
    for (int x = tid; x < 1600; x += 512) e2[x] = Eq[(size_t)l2[x / 100] * 100 + (x % 100)];
    __syncthreads();
    for (int x = tid; x < 1600; x += 512) {
      int r = x / 100, j = x % 100;
      const int* lr = l3 + r * 4;
      float s = Ec[(size_t)lr[0] * 100 + j] + Ec[(size_t)lr[1] * 100 + j] +
                Ec[(size_t)lr[2] * 100 + j] + Ec[(size_t)lr[3] * 100 + j];
      m3[x] = e2[x] + 0.25f * s;
    }
    for (int x = tid; x < 100; x += 512)
      sum1[x] = e0[x] + 0.25f * (e1[x] + e1[100 + x] + e1[200 + x] + e1[300 + x]);
    for (int x = tid; x < 400; x += 512) {
      int k = x / 100, j = x % 100;
      const float* e2k = e2 + k * 400;
      sum4[x] = e1[x] + 0.25f * (e2k[j] + e2k[100 + j] + e2k[200 + j] + e2k[300 + j]);
    }
    __syncthreads();
    // pass1: 2100 outputs as 600 items (row0 solo x100, sum4 4-group x100,
    // m3 four 4-groups x400). 4-group: per j, 1 W load + 4 LDS + 4 fma.
    // 512 threads: max 2 items/thread (4 units) vs 3 (7 units) at 256.
    for (int it = tid; it < 600; it += 512) {
      if (it < 100) {
        int i = it;
        float acc = baggf[i];
        for (int j = 0; j < 100; j++) acc += sum1[j] * waggT[j * 100 + i];
        ne0[i] = tanhf(acc);
      } else {
        const float *in, *W;
        float bia;
        float* dst;
        int i;
        if (it < 200) { i = it - 100; in = sum4; W = waggT + 10000; bia = baggf[100 + i]; dst = ne1 + i; }
        else {
          int gi = (it - 200) / 100;
          i = (it - 200) % 100;
          in = m3 + gi * 400; W = waggT + 20000; bia = baggf[200 + i]; dst = ne2 + gi * 400 + i;
        }
        float a0 = bia, a1 = bia, a2 = bia, a3 = bia;
        for (int j = 0; j < 100; j++) {
          float w = W[j * 100 + i];
          a0 = fmaf(in[j], w, a0);
          a1 = fmaf(in[100 + j], w, a1);
          a2 = fmaf(in[200 + j], w, a2);
          a3 = fmaf(in[300 + j], w, a3);
        }
        dst[0] = tanhf(a0);
        dst[100] = tanhf(a1);
        dst[200] = tanhf(a2);
        dst[300] = tanhf(a3);
      }
    }
    __syncthreads();
    for (int x = tid; x < 100; x += 512)
      sum1[x] = ne0[x] + 0.25f * (ne1[x] + ne1[100 + x] + ne1[200 + x] + ne1[300 + x]);
    for (int x = tid; x < 400; x += 512) {
      int k = x / 100, j = x % 100;
      const float* n2k = ne2 + k * 400;
      sum4[x] = ne1[x] + 0.25f * (n2k[j] + n2k[100 + j] + n2k[200 + j] + n2k[300 + j]);
    }
    __syncthreads();
    // pass2: 500 outputs as 200 items (row0 solo x100, sum4 4-group x100)
    for (int it = tid; it < 200; it += 512) {
      if (it < 100) {
        int i = it;
        float acc = baggf[i];
        for (int j = 0; j < 100; j++) acc += sum1[j] * waggT[j * 100 + i];
        e0[i] = tanhf(acc);
      } else {
        int i = it - 100;
        float bia = baggf[100 + i];
        float a0 = bia, a1 = bia, a2 = bia, a3 = bia;
        for (int j = 0; j < 100; j++) {
          float w = waggT[10000 + j * 100 + i];
          a0 = fmaf(sum4[j], w, a0);
          a1 = fmaf(sum4[100 + j], w, a1);
          a2 = fmaf(sum4[200 + j], w, a2);
          a3 = fmaf(sum4[300 + j], w, a3);
        }
        e1[i] = tanhf(a0);
        e1[100 + i] = tanhf(a1);
        e1[200 + i] = tanhf(a2);
        e1[300 + i] = tanhf(a3);
      }
    }
    __syncthreads();
    for (int x = tid; x < 100; x += 512)
      sum1[x] = e0[x] + 0.25f * (e1[x] + e1[100 + x] + e1[200 + x] + e1[300 + x]);
    __syncthreads();
    for (int o = tid; o < 100; o += 512) {
      float acc = baggf[o];
      for (int j = 0; j < 100; j++) acc += sum1[j] * waggT[j * 100 + o];
      ne0[o] = tanhf(acc);
    }
    __syncthreads();
    for (int o = tid; o < 100; o += 512) {
      float acc = blastf[o];
      for (int j = 0; j < 100; j++) acc += ne0[j] * wlastT[j * 100 + o];
      emq[o] = tanhf(acc);
    }
    __syncthreads();
  } else {
    for (int x = tid; x < 100; x += 512) emq[x] = Eq[(size_t)qt * 100 + x];
    __syncthreads();
  }

  // final pass: 300 outputs as 100 items of 3 (o, o+100, o+200) sharing emq[j]
  const size_t bt = (size_t)b * T_ + t;
  for (int i = tid; i < 100; i += 512) {
    float a0 = erw[rt * 300 + i];
    float a1 = erw[rt * 300 + 100 + i];
    float a2 = erw[rt * 300 + 200 + i];
    for (int j = 0; j < 100; j++) {
      float e = emq[j];
      a0 = fmaf(e, wih1aT[j * 300 + i], a0);
      a1 = fmaf(e, wih1aT[j * 300 + 100 + i], a1);
      a2 = fmaf(e, wih1aT[j * 300 + 200 + i], a2);
    }
    gi1_all[bt * 300 + i] = a0;
    gi1_all[bt * 300 + 100 + i] = a1;
    gi1_all[bt * 300 + 200 + i] = a2;
  }
}

// ---------------------------------------------------------------------------
// Phase B v3 (verbatim R12): W-column sharing on the qtl matvec + shuffle
// top-10.
// ---------------------------------------------------------------------------
__global__ __launch_bounds__(128) void phaseB(
    const float* Eq, const float* Ec, const int* question, const int* cidx, const int* cmask,
    const float* wkeyT, const float* b_key, const float* W_W,
    float* qw_all, int* top10_all)
{
  const int t = blockIdx.x, b = blockIdx.y, tid = threadIdx.x;
  const size_t bt = (size_t)b * T_ + t;
  __shared__ float qcf[500];
  __shared__ float qtl[500];
  __shared__ float qwp[20];
  __shared__ float sval[2];
  __shared__ int sidx[2];
  __shared__ int ci[4], cm[4];

  const int qn = question[b * S_ + t + 1];
  if (tid < 4) { ci[tid] = cidx[qn * KC_ + tid]; cm[tid] = cmask[qn * KC_ + tid]; }
  __syncthreads();

  for (int u = tid; u < 500; u += 128) {
    int row = u / 100, j = u % 100;
    float v;
    if (row == 0) v = Eq[(size_t)qn * 100 + j];
    else {
      int k = row - 1;
      v = cm[k] ? Ec[(size_t)ci[k] * 100 + j] : 0.f;
    }
    qcf[u] = v;
  }
  __syncthreads();
  // qtl matvec: 500 outputs as 100 items of 5 (q=0..4 share wkeyT column i)
  if (tid < 100) {
    const int i = tid;
    float a0 = b_key[i], a1 = a0, a2 = a0, a3 = a0, a4 = a0;
    for (int j = 0; j < 100; j++) {
      float w = wkeyT[j * 100 + i];
      a0 = fmaf(qcf[j], w, a0);
      a1 = fmaf(qcf[100 + j], w, a1);
      a2 = fmaf(qcf[200 + j], w, a2);
      a3 = fmaf(qcf[300 + j], w, a3);
      a4 = fmaf(qcf[400 + j], w, a4);
    }
    qtl[i] = tanhf(a0);
    qtl[100 + i] = tanhf(a1);
    qtl[200 + i] = tanhf(a2);
    qtl[300 + i] = tanhf(a3);
    qtl[400 + i] = tanhf(a4);
  }
  __syncthreads();
  if (tid < 20) {
    int q = tid / 4, part = tid % 4;
    float acc = 0.f;
    for (int j = part * 25; j < part * 25 + 25; j++) acc += qtl[q * 100 + j] * W_W[j];
    qwp[tid] = acc;
  }
  __syncthreads();
  if (tid < 5) qw_all[bt * 5 + tid] = qwp[tid * 4] + qwp[tid * 4 + 1] + qwp[tid * 4 + 2] + qwp[tid * 4 + 3];

  if (t > RK_) {
    float sc = -__builtin_inff();
    if (tid < t) {
      int qs = question[b * S_ + tid];
      float acc = 0.f;
      for (int j = 0; j < 100; j++) acc += Eq[(size_t)qs * 100 + j] * qcf[j];
      sc = acc;
    }
    for (int pass = 0; pass < 10; pass++) {
      float v = sc;
      int vi = tid;
#pragma unroll
      for (int off = 1; off < 64; off <<= 1) {
        float v2 = __shfl_xor(v, off);
        int i2 = __shfl_xor(vi, off);
        if (v2 > v || (v2 == v && i2 < vi)) { v = v2; vi = i2; }
      }
      if ((tid & 63) == 0) { sval[tid >> 6] = v; sidx[tid >> 6] = vi; }
      __syncthreads();
      float v0 = sval[0], v1 = sval[1];
      int i0 = sidx[0], i1 = sidx[1];
      int widx = (v1 > v0 || (v1 == v0 && i1 < i0)) ? i1 : i0;
      if (tid == 0) top10_all[bt * 10 + pass] = widx;
      if (tid == widx) sc = -__builtin_inff();
      __syncthreads();  // sval/sidx reused next pass
    }
  }
}

// bf16 row-dot helper: dot(unpack(w[0..3]), hr[0..31])
__device__ __forceinline__ float bf16_dot32(const uint4 w[4], const float hr[32]) {
  float a = 0.f;
#pragma unroll
  for (int c = 0; c < 4; ++c) {
    uint4 ww = w[c];
    const int e = c * 8;
    a = fmaf(__uint_as_float(ww.x << 16),         hr[e + 0], a);
    a = fmaf(__uint_as_float(ww.x & 0xffff0000u), hr[e + 1], a);
    a = fmaf(__uint_as_float(ww.y << 16),         hr[e + 2], a);
    a = fmaf(__uint_as_float(ww.y & 0xffff0000u), hr[e + 3], a);
    a = fmaf(__uint_as_float(ww.z << 16),         hr[e + 4], a);
    a = fmaf(__uint_as_float(ww.z & 0xffff0000u), hr[e + 5], a);
    a = fmaf(__uint_as_float(ww.w << 16),         hr[e + 6], a);
    a = fmaf(__uint_as_float(ww.w & 0xffff0000u), hr[e + 7], a);
  }
  return a;
}

// ---------------------------------------------------------------------------
// Sequential scan v12 (verified best, ~690us; verbatim R4/R10/R11/R12): 1024
// threads, 3 barriers/step. W_hh1/W_ih2/W_query in LDS (scalar 13-u32 packed
// reads, conflict-free); W_hh2 streamed from L2; g2hist in global ws (rows
// stride 128). R5 (b128 grouping), R6 (2-barrier pipeline) both regressed:
// the loop is intra-phase latency-bound at fixed occupancy.
// Phases:
//   S1: Whh1(LDS) 3-dot+GRU1->h1n [grp<100] | Whh2(L2) 3-dot->gh2 [grp 128-228) -> b1
//   S3: Wih2(LDS) 3-dot+GRU2->g2v [grp<100] | h1 copy [tid 400-500) | og s>=1 [grp 128-178) -> b2
//   S5: kq(LDS) | og s=0 | commits + h2/g2hist updates -> b3
//   S6: wave-0 kw/softmax/store (no trailing barrier; ogs dbuf by parity)
// ---------------------------------------------------------------------------
__global__ __launch_bounds__(1024) void seqk(
    const u32* __restrict__ wcat16, const float* __restrict__ bcat,
    const float* __restrict__ gi1_all, const float* __restrict__ qw_all, const int* __restrict__ top10_all,
    const float* __restrict__ W_W, const float* __restrict__ b_W,
    const float* __restrict__ Eq, const float* __restrict__ Ec, const int* __restrict__ question,
    const int* __restrict__ cidx, const int* __restrict__ cmask,
    const float* __restrict__ h1_init, const float* __restrict__ h2_init, const float* __restrict__ scal,
    float* __restrict__ g2hist_g, float* __restrict__ out)
{
  const int b = blockIdx.x, tid = threadIdx.x;
  const int grp = tid >> 2, sub = tid & 3;  // grp in [0,256)
  const int ptid = tid - 424;               // prefetch lane index
  const uint4* wimg = (const uint4*)wcat16;
  float* const g2h = g2hist_g + (size_t)b * (T_ * 128);  // rows stride 128

  __shared__ float hcomb[200];         // h1 | h2
  __shared__ __align__(16) float h1n[100], g2v[100];
  __shared__ float gh2[300], kqs[100];
  __shared__ float gi1d[2][300];
  __shared__ float qcd[2][500];
  __shared__ float qwd[2][5];
  __shared__ int topd[2][10];
  __shared__ float kwhist[128];
  __shared__ float ogs[2][55];
  __shared__ float bresS[1000];        // [0,600) b_hh1|b_hh2, [600,900) b_ih2, [900,1000) b_query
  __shared__ float wkS[100];
  __shared__ int cidS[8], cid0S[8];
  __shared__ int qn1S, qnS;
  __shared__ u32 whh1S[300 * 52];      // 62.4 KB: W_hh1,   packed [row][sub(4)][13 u32]
  __shared__ u32 wih2S[300 * 52];      // 62.4 KB: W_ih2,   packed [row][sub(4)][13 u32]
  __shared__ u32 wqS[100 * 52];        // 20.8 KB: W_query, packed [row][sub(4)][13 u32]

  for (int x = tid; x < 1000; x += 1024) {
    int src = (x < 600) ? x : ((x < 900) ? (1024 + (x - 600)) : (1536 + (x - 900)));
    bresS[x] = bcat[src];
  }
  if (tid < 100) wkS[tid] = W_W[100 + tid];

  // one-time LDS packs: W_hh1 slots [0,300), W_ih2 slots [1024,1324), W_query [1536,1636)
  for (int x = tid; x < 300 * 52; x += 1024) {
    int s = x / 52, r = x - s * 52;
    int sb = r / 13, k = r - sb * 13;
    whh1S[x] = wcat16[(size_t)s * 64 + sb * 16 + k];
    wih2S[x] = wcat16[(size_t)(1024 + s) * 64 + sb * 16 + k];
  }
  for (int x = tid; x < 100 * 52; x += 1024) {
    int s = x / 52, r = x - s * 52;
    int sb = r / 13, k = r - sb * 13;
    wqS[x] = wcat16[(size_t)(1536 + s) * 64 + sb * 16 + k];
  }

  const float bWv = b_W[0];
  const float kw0 = scal[0];

  if (tid < 100) {
    hcomb[tid] = h1_init[b * 100 + tid];
  } else if (tid < 200) {
    hcomb[tid] = h2_init[b * 100 + (tid - 100)];
  }
  if (tid >= 200 && tid < 328) g2h[tid - 200] = 0.f;  // row 0 of g2hist = zeros
  if (tid < 128) kwhist[tid] = kw0;
  if (tid < 300) gi1d[0][tid] = gi1_all[(size_t)b * T_ * 300 + tid];
  if (tid >= 300 && tid < 305) qwd[0][tid - 300] = qw_all[(size_t)b * T_ * 5 + (tid - 300)];
  if (tid == 306) { qn1S = question[b * S_ + 2]; qnS = question[b * S_ + 3]; }
  if (tid >= 320 && tid < 328) {
    int k = tid - 320, qn0 = question[b * S_ + 1];
    cid0S[k] = (k < 4) ? cidx[qn0 * KC_ + k] : cmask[qn0 * KC_ + k - 4];
  }
  if (tid >= 328 && tid < 336) {
    int k = tid - 328, qn1 = question[b * S_ + 2];
    cidS[k] = (k < 4) ? cidx[qn1 * KC_ + k] : cmask[qn1 * KC_ + k - 4];
  }
  __syncthreads();
  if (tid < 500) {
    int q = tid / 100, j = tid % 100;
    int qn0 = question[b * S_ + 1];
    qcd[0][tid] = (q == 0) ? Eq[(size_t)qn0 * 100 + j]
                           : (cid0S[4 + q - 1] ? Ec[(size_t)cid0S[q - 1] * 100 + j] : 0.f);
  }
  __syncthreads();

  for (int t = 0; t < T_; ++t) {
    const size_t bt = (size_t)b * T_ + t;
    const int cur = t & 1, nxt = cur ^ 1;
    const bool pf = (t + 1) < T_;
    const int qn1 = qn1S, qn2 = qnS;  // stable (committed prior S5, barrier since)

    // ---- TOP: issue ALL t+1 prefetch on tids >= 424 (latency hides under S1) ----
    float pqc = 0.f, pgi = 0.f, pqw = 0.f;
    int ptop = 0, pci = 0, pqn = 0;
    if (pf) {
      if (ptid >= 0 && ptid < 500) {
        int q = ptid / 100, j = ptid % 100;
        pqc = (q == 0) ? Eq[(size_t)qn1 * 100 + j]
                       : (cidS[4 + q - 1] ? Ec[(size_t)cidS[q - 1] * 100 + j] : 0.f);
      }
      if (ptid >= 0 && ptid < 300) pgi = gi1_all[(bt + 1) * 300 + ptid];
      if (tid >= 924 && tid < 929) pqw = qw_all[(bt + 1) * 5 + (tid - 924)];
      if (tid >= 929 && tid < 939 && (t + 1) > RK_) ptop = top10_all[(bt + 1) * 10 + (tid - 929)];
      if (tid >= 939 && tid < 947 && (t + 2) < T_) {
        int k = tid - 939;
        pci = (k < 4) ? cidx[qn2 * KC_ + k] : cmask[qn2 * KC_ + k - 4];
      }
      if (tid == 947) pqn = question[b * S_ + min(t + 4, S_ - 1)];
    }

    // ---- S1: Whh1(LDS)+GRU1 -> h1n [grp<100] | Whh2(L2) -> gh2 [grp 128-228) ----
    if (grp < 100) {
      const int j = grp;
      const u32* wr0 = whh1S + j * 52 + sub * 13;
      const u32* wr1 = wr0 + 100 * 52;
      const u32* wr2 = wr0 + 200 * 52;
      const float* hsrc = hcomb + sub * 25;
      float a0 = 0.f, a1 = 0.f, a2 = 0.f;
#pragma unroll
      for (int k = 0; k < 13; ++k) {
        float h0  = hsrc[2 * k];
        float h1v = (2 * k + 1 < 25) ? hsrc[2 * k + 1] : 0.f;
        u32 w0v = wr0[k], w1v = wr1[k], w2v = wr2[k];
        a0 = fmaf(__uint_as_float(w0v << 16),         h0,  a0);
        a0 = fmaf(__uint_as_float(w0v & 0xffff0000u), h1v, a0);
        a1 = fmaf(__uint_as_float(w1v << 16),         h0,  a1);
        a1 = fmaf(__uint_as_float(w1v & 0xffff0000u), h1v, a1);
        a2 = fmaf(__uint_as_float(w2v << 16),         h0,  a2);
        a2 = fmaf(__uint_as_float(w2v & 0xffff0000u), h1v, a2);
      }
      a0 += __shfl_xor(a0, 1); a0 += __shfl_xor(a0, 2);
      a1 += __shfl_xor(a1, 1); a1 += __shfl_xor(a1, 2);
      a2 += __shfl_xor(a2, 1); a2 += __shfl_xor(a2, 2);
      if (sub == 0) {
        float g0 = a0 + bresS[j], gg1 = a1 + bresS[100 + j], gg2 = a2 + bresS[200 + j];
        float rg = sigmf(gi1d[cur][j] + g0);
        float z  = sigmf(gi1d[cur][100 + j] + gg1);
        float n  = tanhf(gi1d[cur][200 + j] + rg * gg2);
        h1n[j] = (1.f - z) * n + z * hcomb[j];
      }
    } else if (grp >= 128 && grp < 228) {
      const int j = grp - 128;
      const int s0 = 300 + j;
      uint4 w0[4], w1[4], w2[4];
      {
        const uint4* p0 = wimg + (size_t)s0 * 16 + sub * 4;
        const uint4* p1 = wimg + (size_t)(s0 + 100) * 16 + sub * 4;
        const uint4* p2 = wimg + (size_t)(s0 + 200) * 16 + sub * 4;
#pragma unroll
        for (int c = 0; c < 4; ++c) { w0[c] = p0[c]; w1[c] = p1[c]; w2[c] = p2[c]; }
      }
      float hr[32];
#pragma unroll
      for (int c = 25; c < 32; ++c) hr[c] = 0.f;
#pragma unroll
      for (int c = 0; c < 25; ++c) hr[c] = hcomb[100 + sub * 25 + c];
      float a0 = bf16_dot32(w0, hr);
      float a1 = bf16_dot32(w1, hr);
      float a2 = bf16_dot32(w2, hr);
      a0 += __shfl_xor(a0, 1); a0 += __shfl_xor(a0, 2);
      a1 += __shfl_xor(a1, 1); a1 += __shfl_xor(a1, 2);
      a2 += __shfl_xor(a2, 1); a2 += __shfl_xor(a2, 2);
      if (sub == 0) {
        gh2[j]       = a0 + bresS[300 + j];
        gh2[100 + j] = a1 + bresS[400 + j];
        gh2[200 + j] = a2 + bresS[500 + j];
      }
    }
    __syncthreads();  // b1: h1n, gh2 visible

    // ---- S3: Wih2(LDS)+GRU2 -> g2v [grp<100] | h1 copy | og s>=1 [grp 128-178) ----
    if (grp < 100) {
      const int j = grp;
      const u32* wr0 = wih2S + j * 52 + sub * 13;
      const u32* wr1 = wr0 + 100 * 52;
      const u32* wr2 = wr0 + 200 * 52;
      const float* hsrc = h1n + sub * 25;
      float a0 = 0.f, a1 = 0.f, a2 = 0.f;
#pragma unroll
      for (int k = 0; k < 13; ++k) {
        float h0  = hsrc[2 * k];
        float h1v = (2 * k + 1 < 25) ? hsrc[2 * k + 1] : 0.f;
        u32 w0v = wr0[k], w1v = wr1[k], w2v = wr2[k];
        a0 = fmaf(__uint_as_float(w0v << 16),         h0,  a0);
        a0 = fmaf(__uint_as_float(w0v & 0xffff0000u), h1v, a0);
        a1 = fmaf(__uint_as_float(w1v << 16),         h0,  a1);
        a1 = fmaf(__uint_as_float(w1v & 0xffff0000u), h1v, a1);
        a2 = fmaf(__uint_as_float(w2v << 16),         h0,  a2);
        a2 = fmaf(__uint_as_float(w2v & 0xffff0000u), h1v, a2);
      }
      a0 += __shfl_xor(a0, 1); a0 += __shfl_xor(a0, 2);
      a1 += __shfl_xor(a1, 1); a1 += __shfl_xor(a1, 2);
      a2 += __shfl_xor(a2, 1); a2 += __shfl_xor(a2, 2);
      if (sub == 0) {
        float i_r = a0 + bresS[600 + j], i_z = a1 + bresS[700 + j], i_n = a2 + bresS[800 + j];
        float rg = sigmf(i_r + gh2[j]);
        float z  = sigmf(i_z + gh2[100 + j]);
        float n  = tanhf(i_n + rg * gh2[200 + j]);
        g2v[j] = (1.f - z) * n + z * hcomb[100 + j];
      }
    } else if (tid >= 400 && tid < 500) {
      hcomb[tid - 400] = h1n[tid - 400];  // h1 <- h1n (h1n visible after b1)
    } else if (grp >= 128 && grp < 178) {
      int d = grp - 128;  // 0..49
      int s = 1 + d / 5, q = d % 5;
      bool valid = (t > RK_) || (s - 1 < t);
      float a = 0.f;
      if (valid) {
        int idx = (t > RK_) ? topd[cur][s - 1] : (s - 1);
        const float* qcr = &qcd[cur][q * 100 + sub * 25];
        const float* hrow = g2h + (size_t)idx * 128 + sub * 25;
#pragma unroll
        for (int c = 0; c < 25; ++c) a = fmaf(qcr[c], hrow[c], a);
      }
      a += __shfl_xor(a, 1);
      a += __shfl_xor(a, 2);
      if (sub == 0) ogs[cur][s * 5 + q] = a;
    }
    __syncthreads();  // b2: g2v, ogs[cur][5..54] visible

    // ---- S5: kq (grp<100, W_query from LDS) | og s=0 (grp<105) | commits (tid>=424) ----
    if (grp < 100) {
      const u32* wq = wqS + grp * 52 + sub * 13;
      const float* hsrc = g2v + sub * 25;
      float a = 0.f;
#pragma unroll
      for (int k = 0; k < 13; ++k) {
        float h0  = hsrc[2 * k];
        float h1v = (2 * k + 1 < 25) ? hsrc[2 * k + 1] : 0.f;
        u32 wv = wq[k];
        a = fmaf(__uint_as_float(wv << 16),         h0,  a);
        a = fmaf(__uint_as_float(wv & 0xffff0000u), h1v, a);
      }
      a += __shfl_xor(a, 1);
      a += __shfl_xor(a, 2);
      if (sub == 0) kqs[grp] = tanhf(a + bresS[900 + grp]) * wkS[grp];
    } else if (grp < 105) {
      int q = grp - 100;
      const float* qcr = &qcd[cur][q * 100 + sub * 25];
      float a = 0.f;
#pragma unroll
      for (int c = 0; c < 25; ++c) a = fmaf(qcr[c], g2v[sub * 25 + c], a);
      a += __shfl_xor(a, 1);
      a += __shfl_xor(a, 2);
      if (sub == 0) ogs[cur][q] = a;
    }
    if (ptid >= 0) {
      if (pf) {
        if (ptid < 500) qcd[nxt][ptid] = pqc;
        if (ptid < 300) gi1d[nxt][ptid] = pgi;
        if (tid >= 924 && tid < 929) qwd[nxt][tid - 924] = pqw;
        if (tid >= 929 && tid < 939 && (t + 1) > RK_) topd[nxt][tid - 929] = min(T_ - 1, max(0, ptop));
        if (tid >= 939 && tid < 947 && (t + 2) < T_) cidS[tid - 939] = pci;
        if (tid == 947) { qn1S = qn2; qnS = pqn; }
      }
      if (t > 0 && ptid < 100) {
        hcomb[100 + ptid] = g2v[ptid];
        g2h[(size_t)t * 128 + ptid] = g2v[ptid];
      }
    }
    __syncthreads();  // b3: kqs, ogs, commits, state updates visible (vmcnt drained)

    // ---- S6: wave-0 kw reduce + softmax + store (no trailing barrier) ----
    if (tid < 64) {
      float v = (tid < 50) ? (kqs[tid] + kqs[tid + 50]) : 0.f;
      v += __shfl_xor(v, 1);
      v += __shfl_xor(v, 2);
      v += __shfl_xor(v, 4);
      v += __shfl_xor(v, 8);
      v += __shfl_xor(v, 16);
      v += __shfl_xor(v, 32);
      const float kw = v;  // all 64 lanes
      float pq = 0.f;
      if (tid < 5) {
        const float qw = qwd[cur][tid];
        float tmp[11];
        float m = -__builtin_inff();
#pragma unroll
        for (int s = 0; s < 11; ++s) {
          float kws;
          bool valid;
          if (s == 0) { kws = kw; valid = true; }
          else if (t > RK_) { kws = kwhist[topd[cur][s - 1]]; valid = true; }
          else { valid = (s - 1 < t); kws = kwhist[s - 1]; }
          float tv = valid ? (qw + kws + bWv) : NEGV;
          tmp[s] = tv;
          m = fmaxf(m, tv);
        }
        float den = 0.f, num = 0.f;
#pragma unroll
        for (int s = 0; s < 11; ++s) {
          float e = expf(tmp[s] - m);
          den += e;
          num += e * ogs[cur][s * 5 + tid];
        }
        pq = num / den;
      }
      if (tid == 5 && t > 0) kwhist[t] = kw;  // read only by wave 0 (program order)
      float sp = pq;
      sp += __shfl_xor(sp, 1);
      sp += __shfl_xor(sp, 2);
      sp += __shfl_xor(sp, 4);
      if (tid == 0) {
        int col = (t == 0) ? 0 : (t + 1);
        out[b * S_ + col] = sp;
        if (t == 0) out[b * S_ + 1] = 0.f;  // col 1 never written by ref
      }
    }
    // no barrier: next step's S1 writes (h1n/gh2) aren't read by S6; ogs is
    // parity-dbuf and written in S3/S5 (behind b1/b2, which wave 0 must reach
    // after finishing S6); kqs/qwd/topd[cur]/kwhist only touched by wave 0
    // or behind barriers that require wave 0's progress.
  }
}

// ---------------------------------------------------------------------------
extern "C" void kernel_launch(void* const* d_in, const int* in_sizes, int n_in,
                              void* d_out, int out_size, void* d_ws, size_t ws_size,
                              hipStream_t stream)
{
  (void)in_sizes; (void)n_in; (void)out_size; (void)ws_size;
  const float* Eq     = (const float*)d_in[0];
  const float* Ec     = (const float*)d_in[1];
  const float* Er     = (const float*)d_in[2];
  const float* W_ih1  = (const float*)d_in[3];
  const float* W_hh1  = (const float*)d_in[4];
  const float* b_ih1  = (const float*)d_in[5];
  const float* b_hh1  = (const float*)d_in[6];
  const float* W_ih2  = (const float*)d_in[7];
  const float* W_hh2  = (const float*)d_in[8];
  const float* b_ih2  = (const float*)d_in[9];
  const float* b_hh2  = (const float*)d_in[10];
  const float* Wagg   = (const float*)d_in[11];
  const float* bagg   = (const float*)d_in[12];
  const float* W_last = (const float*)d_in[13];
  const float* b_last = (const float*)d_in[14];
  const float* W_query= (const float*)d_in[15];
  const float* b_query= (const float*)d_in[16];
  const float* W_key  = (const float*)d_in[17];
  const float* b_key  = (const float*)d_in[18];
  const float* W_W    = (const float*)d_in[19];
  const float* b_W    = (const float*)d_in[20];
  const float* h1_init= (const float*)d_in[21];
  const float* h2_init= (const float*)d_in[22];
  const int* question = (const int*)d_in[23];
  const int* response = (const int*)d_in[24];
  const int* mask     = (const int*)d_in[25];
  const int* qnb      = (const int*)d_in[26];
  const int* snb      = (const int*)d_in[27];
  const int* cidx     = (const int*)d_in[28];
  const int* cmask    = (const int*)d_in[29];
  float* out = (float*)d_out;

  char* ws = (char*)d_ws;
  size_t off = 0;
  auto alloc = [&](size_t bytes) -> void* {
    void* p = ws + off;
    off += (bytes + 255) & ~(size_t)255;
    return p;
  };
  float* wih1aT = (float*)alloc(30000 * 4);
  float* erw    = (float*)alloc(600 * 4);
  float* waggT  = (float*)alloc(30000 * 4);
  float* wlastT = (float*)alloc(10000 * 4);
  float* wkeyT  = (float*)alloc(10000 * 4);
  float* scal   = (float*)alloc(4);
  u32*   wcat16 = (u32*)alloc(114688 * 4);
  float* bcat   = (float*)alloc(1792 * 4);
  float* gi1_all = (float*)alloc((size_t)B_ * T_ * 300 * 4);
  float* qw_all  = (float*)alloc((size_t)B_ * T_ * 5 * 4);
  int*   top10   = (int*)alloc((size_t)B_ * T_ * 10 * 4);
  float* g2h     = (float*)alloc((size_t)B_ * T_ * 128 * 4);

  hipLaunchKernelGGL(setupk, dim3(128), dim3(256), 0, stream,
      Er, W_ih1, b_ih1, Wagg, W_last, W_key, b_query, W_W, W_query,
      W_hh1, W_hh2, W_ih2, b_hh1, b_hh2, b_ih2,
      wih1aT, erw, waggT, wlastT, wkeyT, scal, wcat16, bcat);

  hipLaunchKernelGGL(phaseA, dim3(T_, B_), dim3(512), 0, stream,
      Eq, Ec, question, response, mask, qnb, snb,
      wih1aT, erw, waggT, wlastT, bagg, b_last, gi1_all);

  hipLaunchKernelGGL(phaseB, dim3(T_, B_), dim3(128), 0, stream,
      Eq, Ec, question, cidx, cmask, wkeyT, b_key, W_W,
      qw_all, top10);

  hipLaunchKernelGGL(seqk, dim3(B_), dim3(1024), 0, stream,
      wcat16, bcat, gi1_all, qw_all, top10, W_W, b_W,
      Eq, Ec, question, cidx, cmask,
      h1_init, h2_init, scal, g2h, out);
}

// Round 15
// 1227.397 us; speedup vs baseline: 1.1315x; 1.1315x over previous
//
#include <hip/hip_runtime.h>
#include <hip/hip_bf16.h>
#include <math.h>

typedef unsigned int u32;

#define B_ 128
#define S_ 128
#define T_ 127
#define D_ 100
#define QN_ 4
#define SN_ 4
#define KC_ 4
#define RK_ 10
#define NEGV -1000000000.0f

__device__ __forceinline__ float sigmf(float x) { return 1.0f / (1.0f + expf(-x)); }

__device__ __forceinline__ u32 f2bfbits(float x) {
  __hip_bfloat16 h = __float2bfloat16(x);
  unsigned short s;
  __builtin_memcpy(&s, &h, 2);
  return (u32)s;
}

// ---------------------------------------------------------------------------
// Setup (unchanged): transposed f32 weights for phaseA/B; erw fold;
// kw0 scalar; bf16 lane-swizzled weight image (1792 slots x 64 u32 = 256B):
//   [0,300): W_hh1 | [300,600): W_hh2 | [1024,1324): W_ih2 | [1536,1636): W_query
// slot bytes: [sub(4)][k(16 u32)], u32 k packs bf16 cols (sub*25+2k, +2k+1).
// ---------------------------------------------------------------------------
__global__ __launch_bounds__(256) void setupk(
    const float* Er, const float* W_ih1, const float* b_ih1,
    const float* Wagg, const float* W_last, const float* W_key,
    const float* b_query, const float* W_W, const float* W_query,
    const float* W_hh1, const float* W_hh2, const float* W_ih2,
    const float* b_hh1, const float* b_hh2, const float* b_ih2,
    float* wih1aT, float* erw, float* waggT, float* wlastT, float* wkeyT,
    float* scal, u32* wcat16, float* bcat)
{
  int gid = blockIdx.x * blockDim.x + threadIdx.x;
  int gsz = gridDim.x * blockDim.x;

  for (int x = gid; x < 30000; x += gsz) {
    int j = x / 300, i = x % 300;
    wih1aT[j * 300 + i] = W_ih1[i * 200 + j];
  }
  for (int x = gid; x < 600; x += gsz) {
    int r = x / 300, i = x % 300;
    float acc = b_ih1[i];
    for (int j = 0; j < 100; j++) acc += Er[r * 100 + j] * W_ih1[i * 200 + 100 + j];
    erw[x] = acc;
  }
  for (int x = gid; x < 30000; x += gsz) {
    int h = x / 10000, rr = x % 10000, j = rr / 100, i = rr % 100;
    waggT[h * 10000 + j * 100 + i] = Wagg[h * 10000 + i * 100 + j];
  }
  for (int x = gid; x < 10000; x += gsz) {
    int j = x / 100, i = x % 100;
    wlastT[j * 100 + i] = W_last[i * 100 + j];
    wkeyT[j * 100 + i] = W_key[i * 100 + j];
  }
  for (int x = gid; x < 114688; x += gsz) {
    int slot = x / 64, rem = x % 64, sbu = rem / 16, k = rem % 16;
    const float* src = nullptr;
    if (slot < 300)                       src = W_hh1 + (size_t)slot * 100;
    else if (slot < 600)                  src = W_hh2 + (size_t)(slot - 300) * 100;
    else if (slot >= 1024 && slot < 1324) src = W_ih2 + (size_t)(slot - 1024) * 100;
    else if (slot >= 1536 && slot < 1636) src = W_query + (size_t)(slot - 1536) * 100;
    u32 lo = 0, hi = 0;
    if (src) {
      int e0 = 2 * k, e1 = 2 * k + 1;
      if (e0 < 25) lo = f2bfbits(src[sbu * 25 + e0]);
      if (e1 < 25) hi = f2bfbits(src[sbu * 25 + e1]);
    }
    wcat16[x] = (hi << 16) | lo;
  }
  for (int x = gid; x < 1792; x += gsz) {
    float v = 0.f;
    if (x < 300) v = b_hh1[x];
    else if (x < 600) v = b_hh2[x - 300];
    else if (x >= 1024 && x < 1324) v = b_ih2[x - 1024];
    else if (x >= 1536 && x < 1636) v = b_query[x - 1536];
    bcat[x] = v;
  }
  if (gid == 0) {
    float acc = 0.f;  // kw of the all-zero hist state: dot(tanh(b_query), Wk_part)
    for (int i = 0; i < 100; i++) acc += tanhf(b_query[i]) * W_W[100 + i];
    scal[0] = acc;
  }
}

// ---------------------------------------------------------------------------
// Phase A v4 (verbatim R11/R12, verified best): R4 scalar base + W-COLUMN
// SHARING at 256 threads. Outputs in different rows of the same pass share W
// columns; 4 rows/thread -> per j: 1 global W load + 4 LDS + 4 fma (2.25
// issues/fma vs 3). No vector loads (R8 failure), no unroll pragmas (R9
// failure), and NOT 512-wide (R14 failure: block concurrency 6->4/CU with
// idle lanes in narrow passes). Numerics bit-identical.
// ---------------------------------------------------------------------------
__global__ __launch_bounds__(256) void phaseA(
    const float* Eq, const float* Ec, const int* question, const int* response, const int* mask,
    const int* qnb, const int* snb,
    const float* wih1aT, const float* erw, const float* waggT, const float* wlastT,
    const float* baggf, const float* blastf, float* gi1_all)
{
  const int t = blockIdx.x, b = blockIdx.y, tid = threadIdx.x;
  __shared__ float e0[100], ne0[100], e1[400], ne1[400];
  __shared__ float e2[1600], ne2[1600], m3[1600];
  __shared__ float sum4[400], sum1[100], emq[100];
  __shared__ int l1[4], l2[16], l3[64];

  const int qt = question[b * S_ + t];
  const int mt = mask[b * S_ + t];
  const int rt = response[b * S_ + t];

  if (mt != 0) {
    if (tid < 4) l1[tid] = qnb[qt * QN_ + tid];
    for (int x = tid; x < 100; x += 256) e0[x] = Eq[(size_t)qt * 100 + x];
    __syncthreads();
    if (tid < 16) l2[tid] = snb[l1[tid >> 2] * SN_ + (tid & 3)];
    for (int x = tid; x < 400; x += 256) e1[x] = Ec[(size_t)l1[x / 100] * 100 + (x % 100)];
    __syncthreads();
    if (tid < 64) l3[tid] = qnb[l2[tid >> 2] * QN_ + (tid & 3)];
    for (int x = tid; x < 1600; x += 256) e2[x] = Eq[(size_t)l2[x / 100] * 100 + (x % 100)];
    __syncthreads();
    for (int x = tid; x < 1600; x += 256) {
      int r = x / 100, j = x % 100;
      const int* lr = l3 + r * 4;
      float s = Ec[(size_t)lr[0] * 100 + j] + Ec[(size_t)lr[1] * 100 + j] +
                Ec[(size_t)lr[2] * 100 + j] + Ec[(size_t)lr[3] * 100 + j];
      m3[x] = e2[x] + 0.25f * s;
    }
    for (int x = tid; x < 100; x += 256)
      sum1[x] = e0[x] + 0.25f * (e1[x] + e1[100 + x] + e1[200 + x] + e1[300 + x]);
    for (int x = tid; x < 400; x += 256) {
      int k = x / 100, j = x % 100;
      const float* e2k = e2 + k * 400;
      sum4[x] = e1[x] + 0.25f * (e2k[j] + e2k[100 + j] + e2k[200 + j] + e2k[300 + j]);
    }
    __syncthreads();
    // pass1: 2100 outputs as 600 items (row0 solo x100, sum4 4-group x100,
    // m3 four 4-groups x400). 4-group: per j, 1 W load + 4 LDS + 4 fma.
    for (int it = tid; it < 600; it += 256) {
      if (it < 100) {
        int i = it;
        float acc = baggf[i];
        for (int j = 0; j < 100; j++) acc += sum1[j] * waggT[j * 100 + i];
        ne0[i] = tanhf(acc);
      } else {
        const float *in, *W;
        float bia;
        float* dst;
        int i;
        if (it < 200) { i = it - 100; in = sum4; W = waggT + 10000; bia = baggf[100 + i]; dst = ne1 + i; }
        else {
          int gi = (it - 200) / 100;
          i = (it - 200) % 100;
          in = m3 + gi * 400; W = waggT + 20000; bia = baggf[200 + i]; dst = ne2 + gi * 400 + i;
        }
        float a0 = bia, a1 = bia, a2 = bia, a3 = bia;
        for (int j = 0; j < 100; j++) {
          float w = W[j * 100 + i];
          a0 = fmaf(in[j], w, a0);
          a1 = fmaf(in[100 + j], w, a1);
          a2 = fmaf(in[200 + j], w, a2);
          a3 = fmaf(in[300 + j], w, a3);
        }
        dst[0] = tanhf(a0);
        dst[100] = tanhf(a1);
        dst[200] = tanhf(a2);
        dst[300] = tanhf(a3);
      }
    }
    __syncthreads();
    for (int x = tid; x < 100; x += 256)
      sum1[x] = ne0[x] + 0.25f * (ne1[x] + ne1[100 + x] + ne1[200 + x] + ne1[300 + x]);
    for (int x = tid; x < 400; x += 256) {
      int k = x / 100, j = x % 100;
      const float* n2k = ne2 + k * 400;
      sum4[x] = ne1[x] + 0.25f * (n2k[j] + n2k[100 + j] + n2k[200 + j] + n2k[300 + j]);
    }
    __syncthreads();
    // pass2: 500 outputs as 200 items (row0 solo x100, sum4 4-group x100)
    for (int it = tid; it < 200; it += 256) {
      if (it < 100) {
        int i = it;
        float acc = baggf[i];
        for (int j = 0; j < 100; j++) acc += sum1[j] * waggT[j * 100 + i];
        e0[i] = tanhf(acc);
      } else {
        int i = it - 100;
        float bia = baggf[100 + i];
        float a0 = bia, a1 = bia, a2 = bia, a3 = bia;
        for (int j = 0; j < 100; j++) {
          float w = waggT[10000 + j * 100 + i];
          a0 = fmaf(sum4[j], w, a0);
          a1 = fmaf(sum4[100 + j], w, a1);
          a2 = fmaf(sum4[200 + j], w, a2);
          a3 = fmaf(sum4[300 + j], w, a3);
        }
        e1[i] = tanhf(a0);
        e1[100 + i] = tanhf(a1);
        e1[200 + i] = tanhf(a2);
        e1[300 + i] = tanhf(a3);
      }
    }
    __syncthreads();
    for (int x = tid; x < 100; x += 256)
      sum1[x] = e0[x] + 0.25f * (e1[x] + e1[100 + x] + e1[200 + x] + e1[300 + x]);
    __syncthreads();
    for (int o = tid; o < 100; o += 256) {
      float acc = baggf[o];
      for (int j = 0; j < 100; j++) acc += sum1[j] * waggT[j * 100 + o];
      ne0[o] = tanhf(acc);
    }
    __syncthreads();
    for (int o = tid; o < 100; o += 256) {
      float acc = blastf[o];
      for (int j = 0; j < 100; j++) acc += ne0[j] * wlastT[j * 100 + o];
      emq[o] = tanhf(acc);
    }
    __syncthreads();
  } else {
    for (int x = tid; x < 100; x += 256) emq[x] = Eq[(size_t)qt * 100 + x];
    __syncthreads();
  }

  // final pass: 300 outputs as 100 items of 3 (o, o+100, o+200) sharing emq[j]
  const size_t bt = (size_t)b * T_ + t;
  for (int i = tid; i < 100; i += 256) {
    float a0 = erw[rt * 300 + i];
    float a1 = erw[rt * 300 + 100 + i];
    float a2 = erw[rt * 300 + 200 + i];
    for (int j = 0; j < 100; j++) {
      float e = emq[j];
      a0 = fmaf(e, wih1aT[j * 300 + i], a0);
      a1 = fmaf(e, wih1aT[j * 300 + 100 + i], a1);
      a2 = fmaf(e, wih1aT[j * 300 + 200 + i], a2);
    }
    gi1_all[bt * 300 + i] = a0;
    gi1_all[bt * 300 + 100 + i] = a1;
    gi1_all[bt * 300 + 200 + i] = a2;
  }
}

// ---------------------------------------------------------------------------
// Phase B v3 (verbatim R12): W-column sharing on the qtl matvec (5 q-rows
// share each wkeyT column) + shuffle top-10.
// ---------------------------------------------------------------------------
__global__ __launch_bounds__(128) void phaseB(
    const float* Eq, const float* Ec, const int* question, const int* cidx, const int* cmask,
    const float* wkeyT, const float* b_key, const float* W_W,
    float* qw_all, int* top10_all)
{
  const int t = blockIdx.x, b = blockIdx.y, tid = threadIdx.x;
  const size_t bt = (size_t)b * T_ + t;
  __shared__ float qcf[500];
  __shared__ float qtl[500];
  __shared__ float qwp[20];
  __shared__ float sval[2];
  __shared__ int sidx[2];
  __shared__ int ci[4], cm[4];

  const int qn = question[b * S_ + t + 1];
  if (tid < 4) { ci[tid] = cidx[qn * KC_ + tid]; cm[tid] = cmask[qn * KC_ + tid]; }
  __syncthreads();

  for (int u = tid; u < 500; u += 128) {
    int row = u / 100, j = u % 100;
    float v;
    if (row == 0) v = Eq[(size_t)qn * 100 + j];
    else {
      int k = row - 1;
      v = cm[k] ? Ec[(size_t)ci[k] * 100 + j] : 0.f;
    }
    qcf[u] = v;
  }
  __syncthreads();
  // qtl matvec: 500 outputs as 100 items of 5 (q=0..4 share wkeyT column i)
  if (tid < 100) {
    const int i = tid;
    float a0 = b_key[i], a1 = a0, a2 = a0, a3 = a0, a4 = a0;
    for (int j = 0; j < 100; j++) {
      float w = wkeyT[j * 100 + i];
      a0 = fmaf(qcf[j], w, a0);
      a1 = fmaf(qcf[100 + j], w, a1);
      a2 = fmaf(qcf[200 + j], w, a2);
      a3 = fmaf(qcf[300 + j], w, a3);
      a4 = fmaf(qcf[400 + j], w, a4);
    }
    qtl[i] = tanhf(a0);
    qtl[100 + i] = tanhf(a1);
    qtl[200 + i] = tanhf(a2);
    qtl[300 + i] = tanhf(a3);
    qtl[400 + i] = tanhf(a4);
  }
  __syncthreads();
  if (tid < 20) {
    int q = tid / 4, part = tid % 4;
    float acc = 0.f;
    for (int j = part * 25; j < part * 25 + 25; j++) acc += qtl[q * 100 + j] * W_W[j];
    qwp[tid] = acc;
  }
  __syncthreads();
  if (tid < 5) qw_all[bt * 5 + tid] = qwp[tid * 4] + qwp[tid * 4 + 1] + qwp[tid * 4 + 2] + qwp[tid * 4 + 3];

  if (t > RK_) {
    float sc = -__builtin_inff();
    if (tid < t) {
      int qs = question[b * S_ + tid];
      float acc = 0.f;
      for (int j = 0; j < 100; j++) acc += Eq[(size_t)qs * 100 + j] * qcf[j];
      sc = acc;
    }
    for (int pass = 0; pass < 10; pass++) {
      float v = sc;
      int vi = tid;
#pragma unroll
      for (int off = 1; off < 64; off <<= 1) {
        float v2 = __shfl_xor(v, off);
        int i2 = __shfl_xor(vi, off);
        if (v2 > v || (v2 == v && i2 < vi)) { v = v2; vi = i2; }
      }
      if ((tid & 63) == 0) { sval[tid >> 6] = v; sidx[tid >> 6] = vi; }
      __syncthreads();
      float v0 = sval[0], v1 = sval[1];
      int i0 = sidx[0], i1 = sidx[1];
      int widx = (v1 > v0 || (v1 == v0 && i1 < i0)) ? i1 : i0;
      if (tid == 0) top10_all[bt * 10 + pass] = widx;
      if (tid == widx) sc = -__builtin_inff();
      __syncthreads();  // sval/sidx reused next pass
    }
  }
}

// bf16 row-dot helper: dot(unpack(w[0..3]), hr[0..31])
__device__ __forceinline__ float bf16_dot32(const uint4 w[4], const float hr[32]) {
  float a = 0.f;
#pragma unroll
  for (int c = 0; c < 4; ++c) {
    uint4 ww = w[c];
    const int e = c * 8;
    a = fmaf(__uint_as_float(ww.x << 16),         hr[e + 0], a);
    a = fmaf(__uint_as_float(ww.x & 0xffff0000u), hr[e + 1], a);
    a = fmaf(__uint_as_float(ww.y << 16),         hr[e + 2], a);
    a = fmaf(__uint_as_float(ww.y & 0xffff0000u), hr[e + 3], a);
    a = fmaf(__uint_as_float(ww.z << 16),         hr[e + 4], a);
    a = fmaf(__uint_as_float(ww.z & 0xffff0000u), hr[e + 5], a);
    a = fmaf(__uint_as_float(ww.w << 16),         hr[e + 6], a);
    a = fmaf(__uint_as_float(ww.w & 0xffff0000u), hr[e + 7], a);
  }
  return a;
}

// ---------------------------------------------------------------------------
// Sequential scan v12 (verified best, ~690us; verbatim R12, single-copy):
// 1024 threads, 3 barriers/step. W_hh1/W_ih2/W_query in LDS (scalar 13-u32
// packed reads, conflict-free); W_hh2 streamed from L2; g2hist in global ws
// (rows stride 128). R5 (b128 grouping), R6 (2-barrier pipeline) both
// regressed: the loop is intra-phase latency-bound at fixed occupancy.
// Phases:
//   S1: Whh1(LDS) 3-dot+GRU1->h1n [grp<100] | Whh2(L2) 3-dot->gh2 [grp 128-228) -> b1
//   S3: Wih2(LDS) 3-dot+GRU2->g2v [grp<100] | h1 copy [tid 400-500) | og s>=1 [grp 128-178) -> b2
//   S5: kq(LDS) | og s=0 | commits + h2/g2hist updates -> b3
//   S6: wave-0 kw/softmax/store (no trailing barrier; ogs dbuf by parity)
// ---------------------------------------------------------------------------
__global__ __launch_bounds__(1024) void seqk(
    const u32* __restrict__ wcat16, const float* __restrict__ bcat,
    const float* __restrict__ gi1_all, const float* __restrict__ qw_all, const int* __restrict__ top10_all,
    const float* __restrict__ W_W, const float* __restrict__ b_W,
    const float* __restrict__ Eq, const float* __restrict__ Ec, const int* __restrict__ question,
    const int* __restrict__ cidx, const int* __restrict__ cmask,
    const float* __restrict__ h1_init, const float* __restrict__ h2_init, const float* __restrict__ scal,
    float* __restrict__ g2hist_g, float* __restrict__ out)
{
  const int b = blockIdx.x, tid = threadIdx.x;
  const int grp = tid >> 2, sub = tid & 3;  // grp in [0,256)
  const int ptid = tid - 424;               // prefetch lane index
  const uint4* wimg = (const uint4*)wcat16;
  float* const g2h = g2hist_g + (size_t)b * (T_ * 128);  // rows stride 128

  __shared__ float hcomb[200];         // h1 | h2
  __shared__ __align__(16) float h1n[100], g2v[100];
  __shared__ float gh2[300], kqs[100];
  __shared__ float gi1d[2][300];
  __shared__ float qcd[2][500];
  __shared__ float qwd[2][5];
  __shared__ int topd[2][10];
  __shared__ float kwhist[128];
  __shared__ float ogs[2][55];
  __shared__ float bresS[1000];        // [0,600) b_hh1|b_hh2, [600,900) b_ih2, [900,1000) b_query
  __shared__ float wkS[100];
  __shared__ int cidS[8], cid0S[8];
  __shared__ int qn1S, qnS;
  __shared__ u32 whh1S[300 * 52];      // 62.4 KB: W_hh1,   packed [row][sub(4)][13 u32]
  __shared__ u32 wih2S[300 * 52];      // 62.4 KB: W_ih2,   packed [row][sub(4)][13 u32]
  __shared__ u32 wqS[100 * 52];        // 20.8 KB: W_query, packed [row][sub(4)][13 u32]

  for (int x = tid; x < 1000; x += 1024) {
    int src = (x < 600) ? x : ((x < 900) ? (1024 + (x - 600)) : (1536 + (x - 900)));
    bresS[x] = bcat[src];
  }
  if (tid < 100) wkS[tid] = W_W[100 + tid];

  // one-time LDS packs: W_hh1 slots [0,300), W_ih2 slots [1024,1324), W_query [1536,1636)
  for (int x = tid; x < 300 * 52; x += 1024) {
    int s = x / 52, r = x - s * 52;
    int sb = r / 13, k = r - sb * 13;
    whh1S[x] = wcat16[(size_t)s * 64 + sb * 16 + k];
    wih2S[x] = wcat16[(size_t)(1024 + s) * 64 + sb * 16 + k];
  }
  for (int x = tid; x < 100 * 52; x += 1024) {
    int s = x / 52, r = x - s * 52;
    int sb = r / 13, k = r - sb * 13;
    wqS[x] = wcat16[(size_t)(1536 + s) * 64 + sb * 16 + k];
  }

  const float bWv = b_W[0];
  const float kw0 = scal[0];

  if (tid < 100) {
    hcomb[tid] = h1_init[b * 100 + tid];
  } else if (tid < 200) {
    hcomb[tid] = h2_init[b * 100 + (tid - 100)];
  }
  if (tid >= 200 && tid < 328) g2h[tid - 200] = 0.f;  // row 0 of g2hist = zeros
  if (tid < 128) kwhist[tid] = kw0;
  if (tid < 300) gi1d[0][tid] = gi1_all[(size_t)b * T_ * 300 + tid];
  if (tid >= 300 && tid < 305) qwd[0][tid - 300] = qw_all[(size_t)b * T_ * 5 + (tid - 300)];
  if (tid == 306) { qn1S = question[b * S_ + 2]; qnS = question[b * S_ + 3]; }
  if (tid >= 320 && tid < 328) {
    int k = tid - 320, qn0 = question[b * S_ + 1];
    cid0S[k] = (k < 4) ? cidx[qn0 * KC_ + k] : cmask[qn0 * KC_ + k - 4];
  }
  if (tid >= 328 && tid < 336) {
    int k = tid - 328, qn1 = question[b * S_ + 2];
    cidS[k] = (k < 4) ? cidx[qn1 * KC_ + k] : cmask[qn1 * KC_ + k - 4];
  }
  __syncthreads();
  if (tid < 500) {
    int q = tid / 100, j = tid % 100;
    int qn0 = question[b * S_ + 1];
    qcd[0][tid] = (q == 0) ? Eq[(size_t)qn0 * 100 + j]
                           : (cid0S[4 + q - 1] ? Ec[(size_t)cid0S[q - 1] * 100 + j] : 0.f);
  }
  __syncthreads();

  for (int t = 0; t < T_; ++t) {
    const size_t bt = (size_t)b * T_ + t;
    const int cur = t & 1, nxt = cur ^ 1;
    const bool pf = (t + 1) < T_;
    const int qn1 = qn1S, qn2 = qnS;  // stable (committed prior S5, barrier since)

    // ---- TOP: issue ALL t+1 prefetch on tids >= 424 (latency hides under S1) ----
    float pqc = 0.f, pgi = 0.f, pqw = 0.f;
    int ptop = 0, pci = 0, pqn = 0;
    if (pf) {
      if (ptid >= 0 && ptid < 500) {
        int q = ptid / 100, j = ptid % 100;
        pqc = (q == 0) ? Eq[(size_t)qn1 * 100 + j]
                       : (cidS[4 + q - 1] ? Ec[(size_t)cidS[q - 1] * 100 + j] : 0.f);
      }
      if (ptid >= 0 && ptid < 300) pgi = gi1_all[(bt + 1) * 300 + ptid];
      if (tid >= 924 && tid < 929) pqw = qw_all[(bt + 1) * 5 + (tid - 924)];
      if (tid >= 929 && tid < 939 && (t + 1) > RK_) ptop = top10_all[(bt + 1) * 10 + (tid - 929)];
      if (tid >= 939 && tid < 947 && (t + 2) < T_) {
        int k = tid - 939;
        pci = (k < 4) ? cidx[qn2 * KC_ + k] : cmask[qn2 * KC_ + k - 4];
      }
      if (tid == 947) pqn = question[b * S_ + min(t + 4, S_ - 1)];
    }

    // ---- S1: Whh1(LDS)+GRU1 -> h1n [grp<100] | Whh2(L2) -> gh2 [grp 128-228) ----
    if (grp < 100) {
      const int j = grp;
      const u32* wr0 = whh1S + j * 52 + sub * 13;
      const u32* wr1 = wr0 + 100 * 52;
      const u32* wr2 = wr0 + 200 * 52;
      const float* hsrc = hcomb + sub * 25;
      float a0 = 0.f, a1 = 0.f, a2 = 0.f;
#pragma unroll
      for (int k = 0; k < 13; ++k) {
        float h0  = hsrc[2 * k];
        float h1v = (2 * k + 1 < 25) ? hsrc[2 * k + 1] : 0.f;
        u32 w0v = wr0[k], w1v = wr1[k], w2v = wr2[k];
        a0 = fmaf(__uint_as_float(w0v << 16),         h0,  a0);
        a0 = fmaf(__uint_as_float(w0v & 0xffff0000u), h1v, a0);
        a1 = fmaf(__uint_as_float(w1v << 16),         h0,  a1);
        a1 = fmaf(__uint_as_float(w1v & 0xffff0000u), h1v, a1);
        a2 = fmaf(__uint_as_float(w2v << 16),         h0,  a2);
        a2 = fmaf(__uint_as_float(w2v & 0xffff0000u), h1v, a2);
      }
      a0 += __shfl_xor(a0, 1); a0 += __shfl_xor(a0, 2);
      a1 += __shfl_xor(a1, 1); a1 += __shfl_xor(a1, 2);
      a2 += __shfl_xor(a2, 1); a2 += __shfl_xor(a2, 2);
      if (sub == 0) {
        float g0 = a0 + bresS[j], gg1 = a1 + bresS[100 + j], gg2 = a2 + bresS[200 + j];
        float rg = sigmf(gi1d[cur][j] + g0);
        float z  = sigmf(gi1d[cur][100 + j] + gg1);
        float n  = tanhf(gi1d[cur][200 + j] + rg * gg2);
        h1n[j] = (1.f - z) * n + z * hcomb[j];
      }
    } else if (grp >= 128 && grp < 228) {
      const int j = grp - 128;
      const int s0 = 300 + j;
      uint4 w0[4], w1[4], w2[4];
      {
        const uint4* p0 = wimg + (size_t)s0 * 16 + sub * 4;
        const uint4* p1 = wimg + (size_t)(s0 + 100) * 16 + sub * 4;
        const uint4* p2 = wimg + (size_t)(s0 + 200) * 16 + sub * 4;
#pragma unroll
        for (int c = 0; c < 4; ++c) { w0[c] = p0[c]; w1[c] = p1[c]; w2[c] = p2[c]; }
      }
      float hr[32];
#pragma unroll
      for (int c = 25; c < 32; ++c) hr[c] = 0.f;
#pragma unroll
      for (int c = 0; c < 25; ++c) hr[c] = hcomb[100 + sub * 25 + c];
      float a0 = bf16_dot32(w0, hr);
      float a1 = bf16_dot32(w1, hr);
      float a2 = bf16_dot32(w2, hr);
      a0 += __shfl_xor(a0, 1); a0 += __shfl_xor(a0, 2);
      a1 += __shfl_xor(a1, 1); a1 += __shfl_xor(a1, 2);
      a2 += __shfl_xor(a2, 1); a2 += __shfl_xor(a2, 2);
      if (sub == 0) {
        gh2[j]       = a0 + bresS[300 + j];
        gh2[100 + j] = a1 + bresS[400 + j];
        gh2[200 + j] = a2 + bresS[500 + j];
      }
    }
    __syncthreads();  // b1: h1n, gh2 visible

    // ---- S3: Wih2(LDS)+GRU2 -> g2v [grp<100] | h1 copy | og s>=1 [grp 128-178) ----
    if (grp < 100) {
      const int j = grp;
      const u32* wr0 = wih2S + j * 52 + sub * 13;
      const u32* wr1 = wr0 + 100 * 52;
      const u32* wr2 = wr0 + 200 * 52;
      const float* hsrc = h1n + sub * 25;
      float a0 = 0.f, a1 = 0.f, a2 = 0.f;
#pragma unroll
      for (int k = 0; k < 13; ++k) {
        float h0  = hsrc[2 * k];
        float h1v = (2 * k + 1 < 25) ? hsrc[2 * k + 1] : 0.f;
        u32 w0v = wr0[k], w1v = wr1[k], w2v = wr2[k];
        a0 = fmaf(__uint_as_float(w0v << 16),         h0,  a0);
        a0 = fmaf(__uint_as_float(w0v & 0xffff0000u), h1v, a0);
        a1 = fmaf(__uint_as_float(w1v << 16),         h0,  a1);
        a1 = fmaf(__uint_as_float(w1v & 0xffff0000u), h1v, a1);
        a2 = fmaf(__uint_as_float(w2v << 16),         h0,  a2);
        a2 = fmaf(__uint_as_float(w2v & 0xffff0000u), h1v, a2);
      }
      a0 += __shfl_xor(a0, 1); a0 += __shfl_xor(a0, 2);
      a1 += __shfl_xor(a1, 1); a1 += __shfl_xor(a1, 2);
      a2 += __shfl_xor(a2, 1); a2 += __shfl_xor(a2, 2);
      if (sub == 0) {
        float i_r = a0 + bresS[600 + j], i_z = a1 + bresS[700 + j], i_n = a2 + bresS[800 + j];
        float rg = sigmf(i_r + gh2[j]);
        float z  = sigmf(i_z + gh2[100 + j]);
        float n  = tanhf(i_n + rg * gh2[200 + j]);
        g2v[j] = (1.f - z) * n + z * hcomb[100 + j];
      }
    } else if (tid >= 400 && tid < 500) {
      hcomb[tid - 400] = h1n[tid - 400];  // h1 <- h1n (h1n visible after b1)
    } else if (grp >= 128 && grp < 178) {
      int d = grp - 128;  // 0..49
      int s = 1 + d / 5, q = d % 5;
      bool valid = (t > RK_) || (s - 1 < t);
      float a = 0.f;
      if (valid) {
        int idx = (t > RK_) ? topd[cur][s - 1] : (s - 1);
        const float* qcr = &qcd[cur][q * 100 + sub * 25];
        const float* hrow = g2h + (size_t)idx * 128 + sub * 25;
#pragma unroll
        for (int c = 0; c < 25; ++c) a = fmaf(qcr[c], hrow[c], a);
      }
      a += __shfl_xor(a, 1);
      a += __shfl_xor(a, 2);
      if (sub == 0) ogs[cur][s * 5 + q] = a;
    }
    __syncthreads();  // b2: g2v, ogs[cur][5..54] visible

    // ---- S5: kq (grp<100, W_query from LDS) | og s=0 (grp<105) | commits (tid>=424) ----
    if (grp < 100) {
      const u32* wq = wqS + grp * 52 + sub * 13;
      const float* hsrc = g2v + sub * 25;
      float a = 0.f;
#pragma unroll
      for (int k = 0; k < 13; ++k) {
        float h0  = hsrc[2 * k];
        float h1v = (2 * k + 1 < 25) ? hsrc[2 * k + 1] : 0.f;
        u32 wv = wq[k];
        a = fmaf(__uint_as_float(wv << 16),         h0,  a);
        a = fmaf(__uint_as_float(wv & 0xffff0000u), h1v, a);
      }
      a += __shfl_xor(a, 1);
      a += __shfl_xor(a, 2);
      if (sub == 0) kqs[grp] = tanhf(a + bresS[900 + grp]) * wkS[grp];
    } else if (grp < 105) {
      int q = grp - 100;
      const float* qcr = &qcd[cur][q * 100 + sub * 25];
      float a = 0.f;
#pragma unroll
      for (int c = 0; c < 25; ++c) a = fmaf(qcr[c], g2v[sub * 25 + c], a);
      a += __shfl_xor(a, 1);
      a += __shfl_xor(a, 2);
      if (sub == 0) ogs[cur][q] = a;
    }
    if (ptid >= 0) {
      if (pf) {
        if (ptid < 500) qcd[nxt][ptid] = pqc;
        if (ptid < 300) gi1d[nxt][ptid] = pgi;
        if (tid >= 924 && tid < 929) qwd[nxt][tid - 924] = pqw;
        if (tid >= 929 && tid < 939 && (t + 1) > RK_) topd[nxt][tid - 929] = min(T_ - 1, max(0, ptop));
        if (tid >= 939 && tid < 947 && (t + 2) < T_) cidS[tid - 939] = pci;
        if (tid == 947) { qn1S = qn2; qnS = pqn; }
      }
      if (t > 0 && ptid < 100) {
        hcomb[100 + ptid] = g2v[ptid];
        g2h[(size_t)t * 128 + ptid] = g2v[ptid];
      }
    }
    __syncthreads();  // b3: kqs, ogs, commits, state updates visible (vmcnt drained)

    // ---- S6: wave-0 kw reduce + softmax + store (no trailing barrier) ----
    if (tid < 64) {
      float v = (tid < 50) ? (kqs[tid] + kqs[tid + 50]) : 0.f;
      v += __shfl_xor(v, 1);
      v += __shfl_xor(v, 2);
      v += __shfl_xor(v, 4);
      v += __shfl_xor(v, 8);
      v += __shfl_xor(v, 16);
      v += __shfl_xor(v, 32);
      const float kw = v;  // all 64 lanes
      float pq = 0.f;
      if (tid < 5) {
        const float qw = qwd[cur][tid];
        float tmp[11];
        float m = -__builtin_inff();
#pragma unroll
        for (int s = 0; s < 11; ++s) {
          float kws;
          bool valid;
          if (s == 0) { kws = kw; valid = true; }
          else if (t > RK_) { kws = kwhist[topd[cur][s - 1]]; valid = true; }
          else { valid = (s - 1 < t); kws = kwhist[s - 1]; }
          float tv = valid ? (qw + kws + bWv) : NEGV;
          tmp[s] = tv;
          m = fmaxf(m, tv);
        }
        float den = 0.f, num = 0.f;
#pragma unroll
        for (int s = 0; s < 11; ++s) {
          float e = expf(tmp[s] - m);
          den += e;
          num += e * ogs[cur][s * 5 + tid];
        }
        pq = num / den;
      }
      if (tid == 5 && t > 0) kwhist[t] = kw;  // read only by wave 0 (program order)
      float sp = pq;
      sp += __shfl_xor(sp, 1);
      sp += __shfl_xor(sp, 2);
      sp += __shfl_xor(sp, 4);
      if (tid == 0) {
        int col = (t == 0) ? 0 : (t + 1);
        out[b * S_ + col] = sp;
        if (t == 0) out[b * S_ + 1] = 0.f;  // col 1 never written by ref
      }
    }
    // no barrier: next step's S1 writes (h1n/gh2) aren't read by S6; ogs is
    // parity-dbuf and written in S3/S5 (behind b1/b2, which wave 0 must reach
    // after finishing S6); kqs/qwd/topd[cur]/kwhist only touched by wave 0
    // or behind barriers that require wave 0's progress.
  }
}

// ---------------------------------------------------------------------------
extern "C" void kernel_launch(void* const* d_in, const int* in_sizes, int n_in,
                              void* d_out, int out_size, void* d_ws, size_t ws_size,
                              hipStream_t stream)
{
  (void)in_sizes; (void)n_in; (void)out_size; (void)ws_size;
  const float* Eq     = (const float*)d_in[0];
  const float* Ec     = (const float*)d_in[1];
  const float* Er     = (const float*)d_in[2];
  const float* W_ih1  = (const float*)d_in[3];
  const float* W_hh1  = (const float*)d_in[4];
  const float* b_ih1  = (const float*)d_in[5];
  const float* b_hh1  = (const float*)d_in[6];
  const float* W_ih2  = (const float*)d_in[7];
  const float* W_hh2  = (const float*)d_in[8];
  const float* b_ih2  = (const float*)d_in[9];
  const float* b_hh2  = (const float*)d_in[10];
  const float* Wagg   = (const float*)d_in[11];
  const float* bagg   = (const float*)d_in[12];
  const float* W_last = (const float*)d_in[13];
  const float* b_last = (const float*)d_in[14];
  const float* W_query= (const float*)d_in[15];
  const float* b_query= (const float*)d_in[16];
  const float* W_key  = (const float*)d_in[17];
  const float* b_key  = (const float*)d_in[18];
  const float* W_W    = (const float*)d_in[19];
  const float* b_W    = (const float*)d_in[20];
  const float* h1_init= (const float*)d_in[21];
  const float* h2_init= (const float*)d_in[22];
  const int* question = (const int*)d_in[23];
  const int* response = (const int*)d_in[24];
  const int* mask     = (const int*)d_in[25];
  const int* qnb      = (const int*)d_in[26];
  const int* snb      = (const int*)d_in[27];
  const int* cidx     = (const int*)d_in[28];
  const int* cmask    = (const int*)d_in[29];
  float* out = (float*)d_out;

  char* ws = (char*)d_ws;
  size_t off = 0;
  auto alloc = [&](size_t bytes) -> void* {
    void* p = ws + off;
    off += (bytes + 255) & ~(size_t)255;
    return p;
  };
  float* wih1aT = (float*)alloc(30000 * 4);
  float* erw    = (float*)alloc(600 * 4);
  float* waggT  = (float*)alloc(30000 * 4);
  float* wlastT = (float*)alloc(10000 * 4);
  float* wkeyT  = (float*)alloc(10000 * 4);
  float* scal   = (float*)alloc(4);
  u32*   wcat16 = (u32*)alloc(114688 * 4);
  float* bcat   = (float*)alloc(1792 * 4);
  float* gi1_all = (float*)alloc((size_t)B_ * T_ * 300 * 4);
  float* qw_all  = (float*)alloc((size_t)B_ * T_ * 5 * 4);
  int*   top10   = (int*)alloc((size_t)B_ * T_ * 10 * 4);
  float* g2h     = (float*)alloc((size_t)B_ * T_ * 128 * 4);

  hipLaunchKernelGGL(setupk, dim3(128), dim3(256), 0, stream,
      Er, W_ih1, b_ih1, Wagg, W_last, W_key, b_query, W_W, W_query,
      W_hh1, W_hh2, W_ih2, b_hh1, b_hh2, b_ih2,
      wih1aT, erw, waggT, wlastT, wkeyT, scal, wcat16, bcat);

  hipLaunchKernelGGL(phaseA, dim3(T_, B_), dim3(256), 0, stream,
      Eq, Ec, question, response, mask, qnb, snb,
      wih1aT, erw, waggT, wlastT, bagg, b_last, gi1_all);

  hipLaunchKernelGGL(phaseB, dim3(T_, B_), dim3(128), 0, stream,
      Eq, Ec, question, cidx, cmask, wkeyT, b_key, W_W,
      qw_all, top10);

  hipLaunchKernelGGL(seqk, dim3(B_), dim3(1024), 0, stream,
      wcat16, bcat, gi1_all, qw_all, top10, W_W, b_W,
      Eq, Ec, question, cidx, cmask,
      h1_init, h2_init, scal, g2h, out);
}